// Round 1
// baseline (1372.742 us; speedup 1.0000x reference)
//
#include <hip/hip_runtime.h>
#include <hip/hip_bf16.h>
#include <stdint.h>

#define T_TOK 2048
#define HD    2048
#define NE    16
#define FF    1024
#define TOPK  4
#define SHF   5632

typedef __attribute__((ext_vector_type(8))) short short8;
typedef __attribute__((ext_vector_type(4))) float f32x4;

typedef const __attribute__((address_space(1))) uint32_t* gp1_t;
typedef __attribute__((address_space(3))) uint32_t* lp3_t;

__device__ __forceinline__ void gload_lds16(const void* g, void* l) {
  __builtin_amdgcn_global_load_lds((gp1_t)g, (lp3_t)l, 16, 0, 0);
}

__device__ __forceinline__ unsigned short f2bf(float f) {
  __hip_bfloat16 h = __float2bfloat16(f);
  return __builtin_bit_cast(unsigned short, h);
}
__device__ __forceinline__ float bf2f(unsigned short u) {
  return __uint_as_float(((uint32_t)u) << 16);
}

// ---------------- prep: x -> bf16, zero moe accumulator + counts ----------------
__global__ __launch_bounds__(256) void k_prep(const float* __restrict__ x,
                                              unsigned short* __restrict__ xb,
                                              float* __restrict__ moe,
                                              int* __restrict__ counts, int n) {
  int i = blockIdx.x * blockDim.x + threadIdx.x;
  int stride = gridDim.x * blockDim.x;
  for (; i < n; i += stride) { xb[i] = f2bf(x[i]); moe[i] = 0.f; }
  if (blockIdx.x == 0 && threadIdx.x < NE) counts[threadIdx.x] = 0;
}

// ---------------- router: logits, top-4, renorm, scatter to expert lists -------
__global__ __launch_bounds__(64) void k_router(
    const float* __restrict__ x, const float* __restrict__ wr,
    const float* __restrict__ wsg, int* __restrict__ counts,
    int* __restrict__ list, float* __restrict__ wlist,
    float* __restrict__ gate_sh) {
  const int t = blockIdx.x;
  const int lane = threadIdx.x;
  const float* xrow = x + (size_t)t * HD;
  float p[NE + 1];
#pragma unroll
  for (int e = 0; e <= NE; ++e) p[e] = 0.f;
  for (int i = lane; i < HD; i += 64) {
    float xv = xrow[i];
    const float* wrow = wr + (size_t)i * NE;
#pragma unroll
    for (int e = 0; e < NE; ++e) p[e] += xv * wrow[e];
    p[NE] += xv * wsg[i];
  }
#pragma unroll
  for (int e = 0; e <= NE; ++e) {
    float v = p[e];
    for (int off = 32; off; off >>= 1) v += __shfl_xor(v, off);
    p[e] = v;
  }
  if (lane == 0) {
    gate_sh[t] = 1.f / (1.f + __expf(-p[NE]));
    float l[NE];
#pragma unroll
    for (int e = 0; e < NE; ++e) l[e] = p[e];
    int ids[TOPK]; float lg[TOPK];
#pragma unroll
    for (int k = 0; k < TOPK; ++k) {
      int best = 0; float bv = l[0];
#pragma unroll
      for (int e = 1; e < NE; ++e) { if (l[e] > bv) { bv = l[e]; best = e; } }
      ids[k] = best; lg[k] = bv; l[best] = -1e30f;
    }
    float m = lg[0], s = 0.f, w[TOPK];
#pragma unroll
    for (int k = 0; k < TOPK; ++k) { w[k] = __expf(lg[k] - m); s += w[k]; }
    float inv = 1.f / s;
#pragma unroll
    for (int k = 0; k < TOPK; ++k) {
      int e = ids[k];
      int pos = atomicAdd(&counts[e], 1);
      list[e * T_TOK + pos] = t;
      wlist[e * T_TOK + pos] = w[k] * inv;
    }
  }
}

// ---------------- offsets (prefix over 16 counts) + weight compaction ----------
__global__ __launch_bounds__(256) void k_offsets(
    const int* __restrict__ counts, int* __restrict__ offsets,
    const float* __restrict__ wlist, float* __restrict__ wpair) {
  __shared__ int soff[NE];
  if (threadIdx.x == 0) {
    int off = 0;
    for (int e = 0; e < NE; ++e) { offsets[e] = off; soff[e] = off; off += counts[e]; }
    offsets[NE] = off;
  }
  __syncthreads();
  for (int idx = threadIdx.x; idx < NE * T_TOK; idx += 256) {
    int e = idx >> 11, pos = idx & (T_TOK - 1);
    if (pos < counts[e]) wpair[soff[e] + pos] = wlist[idx];
  }
}

// ---------------- unified 128x128x64 bf16 MFMA GEMM ---------------------------
// MODE 0: expert gate+up  (A = xb gathered by list; store bf16 to O0/O1 at pair rows)
// MODE 1: expert down     (A = act compact rows; atomicAdd f32 scatter to OF=moe by token)
// MODE 2: shared gate+up  (A = xb direct; store bf16 to O0/O1)
// MODE 3: shared down     (A = sgact direct; OF[t] = moe[t] + gate_sh[t]*acc -> d_out)
template<int MODE>
__global__ __launch_bounds__(256) void k_gemm(
    const unsigned short* __restrict__ A, int lda, int K,
    const float* __restrict__ B0, const float* __restrict__ B1, int ldb, int nsplit,
    size_t strideB,
    unsigned short* __restrict__ O0, unsigned short* __restrict__ O1, int ldo,
    float* __restrict__ OF,
    const int* __restrict__ counts, const int* __restrict__ offsets,
    const int* __restrict__ list,
    const float* __restrict__ gate_sh, const float* __restrict__ moe)
{
  __shared__ unsigned short lA[128 * 64];   // [row][k], 16B-slot XOR swizzle by (row&7)
  __shared__ unsigned short lB[128 * 64];   // [n][k],   8B-slot XOR swizzle by (n&15)
  __shared__ int tokLDS[128];

  const int rb = blockIdx.x, cb = blockIdx.y, e = blockIdx.z;
  const int tid = threadIdx.x, lane = tid & 63, wid = tid >> 6;
  const int wr = wid >> 1, wc = wid & 1;

  int cnt = T_TOK;
  if (MODE == 0 || MODE == 1) {
    cnt = counts[e];
    if (rb * 128 >= cnt) return;
  }

  if (MODE == 0) {
    if (tid < 128) {
      int r = rb * 128 + tid;
      tokLDS[tid] = list[e * T_TOK + (r < cnt ? r : cnt - 1)];
    }
    __syncthreads();
  }

  int arow[4];
#pragma unroll
  for (int i = 0; i < 4; ++i) {
    int r = wid * 32 + i * 8 + (lane >> 3);
    if (MODE == 0) arow[i] = tokLDS[r];
    else if (MODE == 1) { int rr = rb * 128 + r; if (rr >= cnt) rr = cnt - 1; arow[i] = offsets[e] + rr; }
    else arow[i] = rb * 128 + r;
  }
  const int kswz = ((lane & 7) ^ (lane >> 3)) * 8;  // element offset for pre-swizzled source

  const float* Bsel = (cb < nsplit) ? B0 : B1;
  const int cb2 = (cb < nsplit) ? cb : cb - nsplit;
  const float* Bbase = Bsel + ((MODE == 0 || MODE == 1) ? (size_t)e * strideB : (size_t)0) + (size_t)cb2 * 128;

  const int nloc = tid & 127;
  const int khalf = tid >> 7;               // 0/1
  const float* Bcol = Bbase + nloc;
  const int bswz = (nloc & 15) << 3;
  char* lBb = (char*)lB;
  const char* lAb = (const char*)lA;

  f32x4 acc[4][4];
#pragma unroll
  for (int mf = 0; mf < 4; ++mf)
#pragma unroll
    for (int nf = 0; nf < 4; ++nf) acc[mf][nf] = (f32x4){0.f, 0.f, 0.f, 0.f};

  for (int k0 = 0; k0 < K; k0 += 64) {
    // A tile: async global->LDS, linear dest + pre-swizzled per-lane source
#pragma unroll
    for (int i = 0; i < 4; ++i) {
      const unsigned short* src = A + (size_t)arow[i] * lda + (k0 + kswz);
      gload_lds16(src, &lA[(wid * 32 + i * 8) * 64]);
    }
    // B tile: fp32 [K,N] global -> bf16 [n][k] LDS (coalesced dword column loads)
#pragma unroll
    for (int j = 0; j < 8; ++j) {
      int kg = j * 2 + khalf;               // 0..15 (4 k's each)
      size_t krow = (size_t)(k0 + kg * 4) * ldb;
      float f0 = Bcol[krow];
      float f1 = Bcol[krow + (size_t)ldb];
      float f2 = Bcol[krow + 2 * (size_t)ldb];
      float f3 = Bcol[krow + 3 * (size_t)ldb];
      uint32_t lo = (uint32_t)f2bf(f0) | ((uint32_t)f2bf(f1) << 16);
      uint32_t hi = (uint32_t)f2bf(f2) | ((uint32_t)f2bf(f3) << 16);
      *(uint2*)(lBb + nloc * 128 + ((kg * 8) ^ bswz)) = make_uint2(lo, hi);
    }
    __syncthreads();
#pragma unroll
    for (int kk = 0; kk < 2; ++kk) {
      const int kb = kk * 64 + ((lane >> 4) * 16);
      short8 af[4], bf[4];
#pragma unroll
      for (int mf = 0; mf < 4; ++mf) {
        int row = wr * 64 + mf * 16 + (lane & 15);
        af[mf] = *(const short8*)(lAb + row * 128 + (kb ^ ((row & 7) << 4)));
      }
#pragma unroll
      for (int nf = 0; nf < 4; ++nf) {
        int n = wc * 64 + nf * 16 + (lane & 15);
        int sw = (n & 15) << 3;
        union { short8 s; uint2 u[2]; } t;
        t.u[0] = *(const uint2*)(lBb + n * 128 + ((kb + 0) ^ sw));
        t.u[1] = *(const uint2*)(lBb + n * 128 + ((kb + 8) ^ sw));
        bf[nf] = t.s;
      }
#pragma unroll
      for (int mf = 0; mf < 4; ++mf)
#pragma unroll
        for (int nf = 0; nf < 4; ++nf)
          acc[mf][nf] = __builtin_amdgcn_mfma_f32_16x16x32_bf16(af[mf], bf[nf], acc[mf][nf], 0, 0, 0);
    }
    __syncthreads();
  }

  const int g4 = (lane >> 4) * 4;
  const int cL = lane & 15;
  const int colb = cb2 * 128 + wc * 64;
  if (MODE == 0) {
    unsigned short* Out = (cb < nsplit) ? O0 : O1;
    const int obase = offsets[e];
#pragma unroll
    for (int mf = 0; mf < 4; ++mf)
#pragma unroll
      for (int r = 0; r < 4; ++r) {
        int rloc = rb * 128 + wr * 64 + mf * 16 + g4 + r;
        if (rloc < cnt) {
          size_t orow = (size_t)(obase + rloc) * ldo;
#pragma unroll
          for (int nf = 0; nf < 4; ++nf)
            Out[orow + colb + nf * 16 + cL] = f2bf(acc[mf][nf][r]);
        }
      }
  } else if (MODE == 1) {
#pragma unroll
    for (int mf = 0; mf < 4; ++mf)
#pragma unroll
      for (int r = 0; r < 4; ++r) {
        int rloc = rb * 128 + wr * 64 + mf * 16 + g4 + r;
        if (rloc < cnt) {
          int tok = list[e * T_TOK + rloc];
          float* dst = OF + (size_t)tok * HD + colb;
#pragma unroll
          for (int nf = 0; nf < 4; ++nf)
            atomicAdd(&dst[nf * 16 + cL], acc[mf][nf][r]);
        }
      }
  } else if (MODE == 2) {
    unsigned short* Out = (cb < nsplit) ? O0 : O1;
#pragma unroll
    for (int mf = 0; mf < 4; ++mf)
#pragma unroll
      for (int r = 0; r < 4; ++r) {
        int t = rb * 128 + wr * 64 + mf * 16 + g4 + r;
        size_t orow = (size_t)t * ldo;
#pragma unroll
        for (int nf = 0; nf < 4; ++nf)
          Out[orow + colb + nf * 16 + cL] = f2bf(acc[mf][nf][r]);
      }
  } else {
#pragma unroll
    for (int mf = 0; mf < 4; ++mf)
#pragma unroll
      for (int r = 0; r < 4; ++r) {
        int t = rb * 128 + wr * 64 + mf * 16 + g4 + r;
        float g = gate_sh[t];
#pragma unroll
        for (int nf = 0; nf < 4; ++nf) {
          size_t idx = (size_t)t * HD + colb + nf * 16 + cL;
          OF[idx] = moe[idx] + g * acc[mf][nf][r];
        }
      }
  }
}

// ---------------- fused SiLU(g)*u*(weight) elementwise, in place into g --------
__global__ __launch_bounds__(256) void k_silu(
    unsigned short* __restrict__ gq, const unsigned short* __restrict__ uq,
    const float* __restrict__ wrow, long total)
{
  long i = ((long)blockIdx.x * blockDim.x + threadIdx.x) * 4;
  const long stride = (long)gridDim.x * blockDim.x * 4;
  for (; i < total; i += stride) {
    ushort4 gv = *(const ushort4*)(gq + i);
    ushort4 uv = *(const ushort4*)(uq + i);
    float w = wrow ? wrow[i >> 10] : 1.f;   // wrow path only used with ncol=1024
    float a0 = bf2f(gv.x), a1 = bf2f(gv.y), a2 = bf2f(gv.z), a3 = bf2f(gv.w);
    float b0 = bf2f(uv.x), b1 = bf2f(uv.y), b2 = bf2f(uv.z), b3 = bf2f(uv.w);
    ushort4 o;
    o.x = f2bf(a0 / (1.f + __expf(-a0)) * b0 * w);
    o.y = f2bf(a1 / (1.f + __expf(-a1)) * b1 * w);
    o.z = f2bf(a2 / (1.f + __expf(-a2)) * b2 * w);
    o.w = f2bf(a3 / (1.f + __expf(-a3)) * b3 * w);
    *(ushort4*)(gq + i) = o;
  }
}

extern "C" void kernel_launch(void* const* d_in, const int* in_sizes, int n_in,
                              void* d_out, int out_size, void* d_ws, size_t ws_size,
                              hipStream_t stream) {
  const float* x     = (const float*)d_in[0];
  const float* wrout = (const float*)d_in[1];
  const float* wgate = (const float*)d_in[2];
  const float* wup   = (const float*)d_in[3];
  const float* wdown = (const float*)d_in[4];
  const float* wsg   = (const float*)d_in[5];
  const float* wsu   = (const float*)d_in[6];
  const float* wsd   = (const float*)d_in[7];
  const float* wseg  = (const float*)d_in[8];
  float* out = (float*)d_out;

  char* ws = (char*)d_ws;
  unsigned short* xb = (unsigned short*)ws;                       // 8 MB
  char* region1 = ws + (size_t)(8u << 20);
  unsigned short* actg = (unsigned short*)region1;                // 16 MB
  unsigned short* actu = (unsigned short*)(region1 + (size_t)(16u << 20));
  unsigned short* sgg  = (unsigned short*)region1;                // 22 MB (reuses region1)
  unsigned short* sgu  = (unsigned short*)(region1 + (size_t)23068672);
  char* p2 = region1 + (size_t)46137344;
  float* moe = (float*)p2;                                        // 16 MB
  char* p3 = p2 + (size_t)16777216;
  int*   counts  = (int*)p3;
  int*   offsets = (int*)(p3 + 256);
  float* gateS   = (float*)(p3 + 512);
  float* wpair   = (float*)(p3 + 512 + 8192);
  int*   list    = (int*)(p3 + 512 + 8192 + 32768);
  float* wlist   = (float*)(p3 + 512 + 8192 + 32768 + 131072);
  (void)ws_size; (void)in_sizes; (void)n_in; (void)out_size;

  const int n = T_TOK * HD;  // 4194304 (= x elems = moe elems)
  k_prep<<<dim3(4096), dim3(256), 0, stream>>>(x, xb, moe, counts, n);
  k_router<<<dim3(T_TOK), dim3(64), 0, stream>>>(x, wrout, wseg, counts, list, wlist, gateS);
  k_offsets<<<dim3(1), dim3(256), 0, stream>>>(counts, offsets, wlist, wpair);

  // expert gate+up: [pairs,1024]x2 <- gathered x @ w_gate/w_up
  k_gemm<0><<<dim3(16, 16, 16), dim3(256), 0, stream>>>(
      xb, HD, HD, wgate, wup, FF, 8, (size_t)HD * FF, actg, actu, FF,
      (float*)nullptr, counts, offsets, list, (const float*)nullptr, (const float*)nullptr);
  k_silu<<<dim3(4096), dim3(256), 0, stream>>>(actg, actu, wpair, (long)T_TOK * TOPK * FF);
  // expert down: moe[tok] += act @ w_down[e]
  k_gemm<1><<<dim3(16, 16, 16), dim3(256), 0, stream>>>(
      actg, FF, FF, wdown, wdown, HD, 1 << 30, (size_t)FF * HD,
      (unsigned short*)nullptr, (unsigned short*)nullptr, HD,
      moe, counts, offsets, list, (const float*)nullptr, (const float*)nullptr);
  // shared gate+up: [2048,5632]x2 <- x @ w_sh_gate/w_sh_up
  k_gemm<2><<<dim3(16, 88, 1), dim3(256), 0, stream>>>(
      xb, HD, HD, wsg, wsu, SHF, 44, (size_t)0, sgg, sgu, SHF,
      (float*)nullptr, counts, offsets, list, (const float*)nullptr, (const float*)nullptr);
  k_silu<<<dim3(4096), dim3(256), 0, stream>>>(sgg, sgu, (const float*)nullptr, (long)T_TOK * SHF);
  // shared down + final combine: out = moe + sigmoid_gate * (sg @ w_sh_down)
  k_gemm<3><<<dim3(16, 16, 1), dim3(256), 0, stream>>>(
      sgg, SHF, SHF, wsd, wsd, HD, 1 << 30, (size_t)0,
      (unsigned short*)nullptr, (unsigned short*)nullptr, HD,
      out, counts, offsets, list, gateS, moe);
}

// Round 2
// 761.675 us; speedup vs baseline: 1.8023x; 1.8023x over previous
//
#include <hip/hip_runtime.h>
#include <hip/hip_bf16.h>
#include <stdint.h>

#define T_TOK 2048
#define HD    2048
#define NE    16
#define FF    1024
#define TOPK  4
#define SHF   5632

typedef __attribute__((ext_vector_type(8))) short short8;
typedef __attribute__((ext_vector_type(4))) float f32x4;

typedef const __attribute__((address_space(1))) uint32_t* gp1_t;
typedef __attribute__((address_space(3))) uint32_t* lp3_t;

__device__ __forceinline__ void gload_lds16(const void* g, void* l) {
  __builtin_amdgcn_global_load_lds((gp1_t)g, (lp3_t)l, 16, 0, 0);
}

__device__ __forceinline__ unsigned short f2bf(float f) {
  __hip_bfloat16 h = __float2bfloat16(f);
  return __builtin_bit_cast(unsigned short, h);
}
__device__ __forceinline__ float bf2f(unsigned short u) {
  return __uint_as_float(((uint32_t)u) << 16);
}

// ---------------- prep: x -> bf16, zero moe accumulator + counts ----------------
__global__ __launch_bounds__(256) void k_prep(const float* __restrict__ x,
                                              unsigned short* __restrict__ xb,
                                              float* __restrict__ moe,
                                              int* __restrict__ counts, int n) {
  int i = blockIdx.x * blockDim.x + threadIdx.x;
  int stride = gridDim.x * blockDim.x;
  for (; i < n; i += stride) { xb[i] = f2bf(x[i]); moe[i] = 0.f; }
  if (blockIdx.x == 0 && threadIdx.x < NE) counts[threadIdx.x] = 0;
}

// ---------------- weight transpose+cast: [b][K][N] fp32 -> [b][N][K] bf16 ------
__global__ __launch_bounds__(256) void k_transpose(const float* __restrict__ src,
    unsigned short* __restrict__ dst, int K, int N) {
  __shared__ unsigned short tile[64][72];
  const int k0 = blockIdx.x * 64;
  const int n0 = blockIdx.y * 64;
  const size_t boff = (size_t)blockIdx.z * K * N;
  src += boff; dst += boff;
  const int t = threadIdx.x;
  const int c4 = (t & 15) * 4;       // n within tile
  const int kr0 = (t >> 4) * 4;      // k row base
#pragma unroll
  for (int j = 0; j < 4; ++j) {
    int kr = kr0 + j;
    float4 v = *(const float4*)(src + (size_t)(k0 + kr) * N + n0 + c4);
    tile[c4 + 0][kr] = f2bf(v.x);
    tile[c4 + 1][kr] = f2bf(v.y);
    tile[c4 + 2][kr] = f2bf(v.z);
    tile[c4 + 3][kr] = f2bf(v.w);
  }
  __syncthreads();
  const int nr = t >> 2;             // 0..63
  const int kc = (t & 3) * 8;        // chunk of 8 bf16
  unsigned short* orow = dst + (size_t)(n0 + nr) * K + k0;
  *(short8*)(orow + kc)      = *(const short8*)(&tile[nr][kc]);
  *(short8*)(orow + kc + 32) = *(const short8*)(&tile[nr][kc + 32]);
}

// ---------------- router: logits, top-4, renorm, scatter to expert lists -------
__global__ __launch_bounds__(64) void k_router(
    const float* __restrict__ x, const float* __restrict__ wr,
    const float* __restrict__ wsg, int* __restrict__ counts,
    int* __restrict__ list, float* __restrict__ wlist,
    float* __restrict__ gate_sh) {
  const int t = blockIdx.x;
  const int lane = threadIdx.x;
  const float* xrow = x + (size_t)t * HD;
  float p[NE + 1];
#pragma unroll
  for (int e = 0; e <= NE; ++e) p[e] = 0.f;
  for (int i = lane; i < HD; i += 64) {
    float xv = xrow[i];
    const float* wrow = wr + (size_t)i * NE;
#pragma unroll
    for (int e = 0; e < NE; ++e) p[e] += xv * wrow[e];
    p[NE] += xv * wsg[i];
  }
#pragma unroll
  for (int e = 0; e <= NE; ++e) {
    float v = p[e];
    for (int off = 32; off; off >>= 1) v += __shfl_xor(v, off);
    p[e] = v;
  }
  if (lane == 0) {
    gate_sh[t] = 1.f / (1.f + __expf(-p[NE]));
    float l[NE];
#pragma unroll
    for (int e = 0; e < NE; ++e) l[e] = p[e];
    int ids[TOPK]; float lg[TOPK];
#pragma unroll
    for (int k = 0; k < TOPK; ++k) {
      int best = 0; float bv = l[0];
#pragma unroll
      for (int e = 1; e < NE; ++e) { if (l[e] > bv) { bv = l[e]; best = e; } }
      ids[k] = best; lg[k] = bv; l[best] = -1e30f;
    }
    float m = lg[0], s = 0.f, w[TOPK];
#pragma unroll
    for (int k = 0; k < TOPK; ++k) { w[k] = __expf(lg[k] - m); s += w[k]; }
    float inv = 1.f / s;
#pragma unroll
    for (int k = 0; k < TOPK; ++k) {
      int e = ids[k];
      int pos = atomicAdd(&counts[e], 1);
      list[e * T_TOK + pos] = t;
      wlist[e * T_TOK + pos] = w[k] * inv;
    }
  }
}

// ---------------- offsets (prefix over 16 counts) + weight compaction ----------
__global__ __launch_bounds__(256) void k_offsets(
    const int* __restrict__ counts, int* __restrict__ offsets,
    const float* __restrict__ wlist, float* __restrict__ wpair) {
  __shared__ int soff[NE];
  if (threadIdx.x == 0) {
    int off = 0;
    for (int e = 0; e < NE; ++e) { offsets[e] = off; soff[e] = off; off += counts[e]; }
    offsets[NE] = off;
  }
  __syncthreads();
  for (int idx = threadIdx.x; idx < NE * T_TOK; idx += 256) {
    int e = idx >> 11, pos = idx & (T_TOK - 1);
    if (pos < counts[e]) wpair[soff[e] + pos] = wlist[idx];
  }
}

// ---------------- unified 128x128x64 bf16 MFMA GEMM (B^T bf16 [N,K]) ----------
// grid: x = column-block (cb), y = row-block (rb), z = expert
// MODE 0: expert gate+up  (A = xb gathered by list; bf16 out at compact rows)
// MODE 1: expert down     (A = act compact rows; atomicAdd f32 scatter to moe)
// MODE 2: shared gate+up  (A = xb direct; bf16 out)
// MODE 3: shared down     (A = sgact; OF[t] = moe[t] + gate_sh[t]*acc -> d_out)
template<int MODE>
__global__ __launch_bounds__(256) void k_gemm(
    const unsigned short* __restrict__ A, int lda, int K,
    const unsigned short* __restrict__ B0, const unsigned short* __restrict__ B1,
    int nsplit, size_t strideB,
    unsigned short* __restrict__ O0, unsigned short* __restrict__ O1, int ldo,
    float* __restrict__ OF,
    const int* __restrict__ counts, const int* __restrict__ offsets,
    const int* __restrict__ list,
    const float* __restrict__ gate_sh, const float* __restrict__ moe)
{
  __shared__ unsigned short lA[128 * 64];   // [row][k], 16B-chunk XOR swizzle by (row&7)
  __shared__ unsigned short lB[128 * 64];   // [n][k],   same swizzle
  __shared__ int tokLDS[128];

  const int cb = blockIdx.x, rb = blockIdx.y, e = blockIdx.z;
  const int tid = threadIdx.x, lane = tid & 63, wid = tid >> 6;
  const int wr = wid >> 1, wc = wid & 1;

  int cnt = T_TOK;
  if (MODE == 0 || MODE == 1) {
    cnt = counts[e];
    if (rb * 128 >= cnt) return;
  }

  if (MODE == 0) {
    if (tid < 128) {
      int r = rb * 128 + tid;
      tokLDS[tid] = list[e * T_TOK + (r < cnt ? r : cnt - 1)];
    }
    __syncthreads();
  }

  const int r3 = lane >> 3;                         // row within 8-row group
  const int kswz = ((lane & 7) ^ r3) * 8;           // pre-swizzled source chunk

  const unsigned short* Bsel = (cb < nsplit) ? B0 : B1;
  const int cb2 = (cb < nsplit) ? cb : cb - nsplit;
  const unsigned short* Bbase = Bsel +
      ((MODE == 0 || MODE == 1) ? (size_t)e * strideB : (size_t)0);

  const unsigned short* aSrc[4];
  const unsigned short* bSrc[4];
  unsigned short* ldsA[4];
  unsigned short* ldsB[4];
#pragma unroll
  for (int i = 0; i < 4; ++i) {
    int rloc = wid * 32 + i * 8 + r3;
    int arow;
    if (MODE == 0) arow = tokLDS[rloc];
    else if (MODE == 1) { int rr = rb * 128 + rloc; if (rr >= cnt) rr = cnt - 1; arow = offsets[e] + rr; }
    else arow = rb * 128 + rloc;
    aSrc[i] = A + (size_t)arow * lda + kswz;
    bSrc[i] = Bbase + (size_t)(cb2 * 128 + rloc) * K + kswz;
    ldsA[i] = &lA[(wid * 32 + i * 8) * 64];
    ldsB[i] = &lB[(wid * 32 + i * 8) * 64];
  }

  const char* lAb = (const char*)lA;
  const char* lBb = (const char*)lB;

  f32x4 acc[4][4];
#pragma unroll
  for (int mf = 0; mf < 4; ++mf)
#pragma unroll
    for (int nf = 0; nf < 4; ++nf) acc[mf][nf] = (f32x4){0.f, 0.f, 0.f, 0.f};

  for (int k0 = 0; k0 < K; k0 += 64) {
#pragma unroll
    for (int i = 0; i < 4; ++i) {
      gload_lds16(aSrc[i] + k0, ldsA[i]);
      gload_lds16(bSrc[i] + k0, ldsB[i]);
    }
    __syncthreads();
#pragma unroll
    for (int kk = 0; kk < 2; ++kk) {
      const int kb = kk * 64 + ((lane >> 4) * 16);
      short8 af[4], bf[4];
#pragma unroll
      for (int mf = 0; mf < 4; ++mf) {
        int row = wr * 64 + mf * 16 + (lane & 15);
        af[mf] = *(const short8*)(lAb + row * 128 + (kb ^ ((row & 7) << 4)));
      }
#pragma unroll
      for (int nf = 0; nf < 4; ++nf) {
        int n = wc * 64 + nf * 16 + (lane & 15);
        bf[nf] = *(const short8*)(lBb + n * 128 + (kb ^ ((n & 7) << 4)));
      }
#pragma unroll
      for (int mf = 0; mf < 4; ++mf)
#pragma unroll
        for (int nf = 0; nf < 4; ++nf)
          acc[mf][nf] = __builtin_amdgcn_mfma_f32_16x16x32_bf16(af[mf], bf[nf], acc[mf][nf], 0, 0, 0);
    }
    __syncthreads();
  }

  const int g4 = (lane >> 4) * 4;
  const int cL = lane & 15;
  const int colb = cb2 * 128 + wc * 64;
  if (MODE == 0) {
    unsigned short* Out = (cb < nsplit) ? O0 : O1;
    const int obase = offsets[e];
#pragma unroll
    for (int mf = 0; mf < 4; ++mf)
#pragma unroll
      for (int r = 0; r < 4; ++r) {
        int rloc = rb * 128 + wr * 64 + mf * 16 + g4 + r;
        if (rloc < cnt) {
          size_t orow = (size_t)(obase + rloc) * ldo;
#pragma unroll
          for (int nf = 0; nf < 4; ++nf)
            Out[orow + colb + nf * 16 + cL] = f2bf(acc[mf][nf][r]);
        }
      }
  } else if (MODE == 1) {
#pragma unroll
    for (int mf = 0; mf < 4; ++mf)
#pragma unroll
      for (int r = 0; r < 4; ++r) {
        int rloc = rb * 128 + wr * 64 + mf * 16 + g4 + r;
        if (rloc < cnt) {
          int tok = list[e * T_TOK + rloc];
          float* dst = OF + (size_t)tok * HD + colb;
#pragma unroll
          for (int nf = 0; nf < 4; ++nf)
            atomicAdd(&dst[nf * 16 + cL], acc[mf][nf][r]);
        }
      }
  } else if (MODE == 2) {
    unsigned short* Out = (cb < nsplit) ? O0 : O1;
#pragma unroll
    for (int mf = 0; mf < 4; ++mf)
#pragma unroll
      for (int r = 0; r < 4; ++r) {
        int t = rb * 128 + wr * 64 + mf * 16 + g4 + r;
        size_t orow = (size_t)t * ldo;
#pragma unroll
        for (int nf = 0; nf < 4; ++nf)
          Out[orow + colb + nf * 16 + cL] = f2bf(acc[mf][nf][r]);
      }
  } else {
#pragma unroll
    for (int mf = 0; mf < 4; ++mf)
#pragma unroll
      for (int r = 0; r < 4; ++r) {
        int t = rb * 128 + wr * 64 + mf * 16 + g4 + r;
        float g = gate_sh[t];
#pragma unroll
        for (int nf = 0; nf < 4; ++nf) {
          size_t idx = (size_t)t * HD + colb + nf * 16 + cL;
          OF[idx] = moe[idx] + g * acc[mf][nf][r];
        }
      }
  }
}

// ---------------- fused SiLU(g)*u*(weight) elementwise, in place into g --------
__global__ __launch_bounds__(256) void k_silu(
    unsigned short* __restrict__ gq, const unsigned short* __restrict__ uq,
    const float* __restrict__ wrow, long total)
{
  long i = ((long)blockIdx.x * blockDim.x + threadIdx.x) * 4;
  const long stride = (long)gridDim.x * blockDim.x * 4;
  for (; i < total; i += stride) {
    ushort4 gv = *(const ushort4*)(gq + i);
    ushort4 uv = *(const ushort4*)(uq + i);
    float w = wrow ? wrow[i >> 10] : 1.f;   // wrow path only used with ncol=1024
    float a0 = bf2f(gv.x), a1 = bf2f(gv.y), a2 = bf2f(gv.z), a3 = bf2f(gv.w);
    float b0 = bf2f(uv.x), b1 = bf2f(uv.y), b2 = bf2f(uv.z), b3 = bf2f(uv.w);
    ushort4 o;
    o.x = f2bf(a0 / (1.f + __expf(-a0)) * b0 * w);
    o.y = f2bf(a1 / (1.f + __expf(-a1)) * b1 * w);
    o.z = f2bf(a2 / (1.f + __expf(-a2)) * b2 * w);
    o.w = f2bf(a3 / (1.f + __expf(-a3)) * b3 * w);
    *(ushort4*)(gq + i) = o;
  }
}

extern "C" void kernel_launch(void* const* d_in, const int* in_sizes, int n_in,
                              void* d_out, int out_size, void* d_ws, size_t ws_size,
                              hipStream_t stream) {
  const float* x     = (const float*)d_in[0];
  const float* wrout = (const float*)d_in[1];
  const float* wgate = (const float*)d_in[2];
  const float* wup   = (const float*)d_in[3];
  const float* wdown = (const float*)d_in[4];
  const float* wsg   = (const float*)d_in[5];
  const float* wsu   = (const float*)d_in[6];
  const float* wsd   = (const float*)d_in[7];
  const float* wseg  = (const float*)d_in[8];
  float* out = (float*)d_out;

  char* ws = (char*)d_ws;
  unsigned short* xb = (unsigned short*)ws;                       // 8 MB
  char* region1 = ws + (size_t)(8u << 20);                        // 46 MB act/sg union
  unsigned short* actg = (unsigned short*)region1;                // 16 MB
  unsigned short* actu = (unsigned short*)(region1 + (size_t)(16u << 20));
  unsigned short* sgg  = (unsigned short*)region1;                // 22 MB (reuses region1)
  unsigned short* sgu  = (unsigned short*)(region1 + (size_t)23068672);
  char* p2 = region1 + (size_t)46137344;
  float* moe = (float*)p2;                                        // 16 MB
  char* p3 = p2 + (size_t)16777216;
  int*   counts  = (int*)p3;
  int*   offsets = (int*)(p3 + 256);
  float* gateS   = (float*)(p3 + 512);
  float* wpair   = (float*)(p3 + 512 + 8192);
  int*   list    = (int*)(p3 + 512 + 8192 + 32768);
  float* wlist   = (float*)(p3 + 512 + 8192 + 32768 + 131072);
  char* p4 = p3 + (size_t)(1u << 20);
  unsigned short* W1 = (unsigned short*)p4;                       // 64 MB
  unsigned short* W2 = (unsigned short*)(p4 + (size_t)(64u << 20)); // 64 MB
  (void)ws_size; (void)in_sizes; (void)n_in; (void)out_size;

  const int n = T_TOK * HD;
  k_prep<<<dim3(4096), dim3(256), 0, stream>>>(x, xb, moe, counts, n);
  k_router<<<dim3(T_TOK), dim3(64), 0, stream>>>(x, wrout, wseg, counts, list, wlist, gateS);
  k_offsets<<<dim3(1), dim3(256), 0, stream>>>(counts, offsets, wlist, wpair);

  // transpose+cast w_gate, w_up: [16][2048][1024] -> bf16 [16][1024][2048]
  k_transpose<<<dim3(32, 16, 16), dim3(256), 0, stream>>>(wgate, W1, HD, FF);
  k_transpose<<<dim3(32, 16, 16), dim3(256), 0, stream>>>(wup,   W2, HD, FF);

  // expert gate+up: compact [pairs,1024]x2 <- gathered x @ w_gate/w_up
  k_gemm<0><<<dim3(16, 16, 16), dim3(256), 0, stream>>>(
      xb, HD, HD, W1, W2, 8, (size_t)HD * FF, actg, actu, FF,
      (float*)nullptr, counts, offsets, list, (const float*)nullptr, (const float*)nullptr);
  k_silu<<<dim3(4096), dim3(256), 0, stream>>>(actg, actu, wpair, (long)T_TOK * TOPK * FF);

  // transpose+cast w_down: [16][1024][2048] -> bf16 [16][2048][1024] (reuse W1)
  k_transpose<<<dim3(16, 32, 16), dim3(256), 0, stream>>>(wdown, W1, FF, HD);
  // expert down: moe[tok] += act @ w_down[e]
  k_gemm<1><<<dim3(16, 16, 16), dim3(256), 0, stream>>>(
      actg, FF, FF, W1, W1, 1 << 30, (size_t)FF * HD,
      (unsigned short*)nullptr, (unsigned short*)nullptr, HD,
      moe, counts, offsets, list, (const float*)nullptr, (const float*)nullptr);

  // transpose+cast shared weights (W2: sh_gate | sh_up ; W1: sh_down)
  unsigned short* WsgT = W2;                         // 5632 x 2048 bf16 = 22 MB
  unsigned short* WsuT = W2 + (size_t)SHF * HD;      // 22 MB
  unsigned short* WsdT = W1;                         // 2048 x 5632 bf16 = 22 MB
  k_transpose<<<dim3(32, 88, 1), dim3(256), 0, stream>>>(wsg, WsgT, HD, SHF);
  k_transpose<<<dim3(32, 88, 1), dim3(256), 0, stream>>>(wsu, WsuT, HD, SHF);
  k_transpose<<<dim3(88, 32, 1), dim3(256), 0, stream>>>(wsd, WsdT, SHF, HD);

  // shared gate+up: [2048,5632]x2 <- x @ w_sh_gate/w_sh_up
  k_gemm<2><<<dim3(88, 16, 1), dim3(256), 0, stream>>>(
      xb, HD, HD, WsgT, WsuT, 44, (size_t)SHF * HD, sgg, sgu, SHF,
      (float*)nullptr, counts, offsets, list, (const float*)nullptr, (const float*)nullptr);
  k_silu<<<dim3(4096), dim3(256), 0, stream>>>(sgg, sgu, (const float*)nullptr, (long)T_TOK * SHF);

  // shared down + final combine: out = moe + sigmoid_gate * (sg @ w_sh_down)
  k_gemm<3><<<dim3(16, 16, 1), dim3(256), 0, stream>>>(
      sgg, SHF, SHF, WsdT, WsdT, 1 << 30, (size_t)0,
      (unsigned short*)nullptr, (unsigned short*)nullptr, HD,
      out, counts, offsets, list, gateS, moe);
}